// Round 17
// baseline (3853.129 us; speedup 1.0000x reference)
//
#include <hip/hip_runtime.h>
#include <cmath>

#define V_ 50257
#define D_ 640
#define NL_ 16
#define DF_ 2560
#define R_ 24
#define DG_ 256
#define PLU_ 276
#define PLUP_ 288
#define B_ 4
#define L_ 1024
#define M_ (B_*L_)
#define EPS_ 1e-6f
#define LN_EPS_ 1e-5f

typedef __bf16 bf16x8 __attribute__((ext_vector_type(8)));
typedef float f32x4 __attribute__((ext_vector_type(4)));

__device__ __forceinline__ float gelu_exact(float x) {
    return 0.5f * x * (1.0f + erff(x * 0.70710678118654752f));
}
__device__ __forceinline__ float sigmoid_f(float x) {
    return 1.0f / (1.0f + expf(-x));
}
__device__ __forceinline__ ushort f2b(float f) {
    union { float f; unsigned u; } v; v.f = f;
    unsigned u = v.u;
    return (ushort)((u + 0x7FFFu + ((u >> 16) & 1u)) >> 16);
}
__device__ __forceinline__ float b2f(ushort b) {
    union { unsigned u; float f; } v; v.u = ((unsigned)b) << 16;
    return v.f;
}
__device__ __forceinline__ ushort4 f4b4(float4 v) {
    ushort4 o;
    o.x = f2b(v.x); o.y = f2b(v.y); o.z = f2b(v.z); o.w = f2b(v.w);
    return o;
}

#define GLOAD16(gptr, lptr) \
    __builtin_amdgcn_global_load_lds((const __attribute__((address_space(1))) void*)(gptr), \
                                     (__attribute__((address_space(3))) void*)(lptr), 16, 0, 0)

// LEDGER:
// R4: XCD remap regressed (lm_head FETCH 288->830MB). Natural blockIdx order.
// R2->R3: LDS XOR-swizzle: SQ_LDS_BANK_CONFLICT 3.2e7 -> 0. Keep.
// R6,R9 (races) + R12,R13 (correct w/ lgkm-fence but SLOWER): 3-stage
//     counted-vmcnt pipelining CLOSED. Schedule is 2-phase:
//     {STAGE(next); ds_read+MFMA(cur); vmcnt(0); s_barrier}.
// R7: coalesced LDS-transpose f32 epilogue for lm_head. Keep.
// R8: gp2 linearity fusion (credsum before gp2, 7x FLOP cut): 4686->4191.
// R10: gate epilogue reads h/g from bf16 hgb: 4191->4079.
// R11: lm_head 256x128 + nontemporal stores: 4079->4047. (lm_head now runs
//     537 TF ~= 90% of the m97-structure ceiling at K=640; structural.)
// R14: gp1 tail fix + vectorized wconv/cvt/embed + merged plucker: ->3972.
// R15: occupancy lever gate/fc2/gp2 -> 64x64 tiles: 3972->3785.
// R16: occupancy lever fc1 -> 128x64 (1280 blocks): 3785->3743.
// R17: credsum FOLDED into gp2's A-staging (reg-staged 7-slice masked
//     average, ds_write swizzled; __syncthreads sync -- compiler emits the
//     full vmcnt+lgkm drain, no hand sync). Deletes 16 launches + crb.

// ---------------------------------------------------------------------------
// 128x128 tile, 4 waves (2x2). 2-phase pipeline. EPI: 1 = gelu->bf16; 4 = bf16
// (retained; unused by default schedule)
// ---------------------------------------------------------------------------
#define AS_(b) (shmem + (b) * 4096)
#define BS_(b) (shmem + 8192 + (b) * 4096)
#define STAGE128(b, k0) do { \
    GLOAD16(A + (size_t)(bm + w * 32 + srow) * (size_t)K + ((k0) + scol), AS_(b) + (w * 32) * 32); \
    GLOAD16(A + (size_t)(bm + w * 32 + 16 + srow) * (size_t)K + ((k0) + scol), AS_(b) + (w * 32 + 16) * 32); \
    int rb0_ = bn + w * 32 + srow;      if (rb0_ > N - 1) rb0_ = N - 1; \
    int rb1_ = bn + w * 32 + 16 + srow; if (rb1_ > N - 1) rb1_ = N - 1; \
    GLOAD16(W + (size_t)rb0_ * (size_t)K + ((k0) + scol), BS_(b) + (w * 32) * 32); \
    GLOAD16(W + (size_t)rb1_ * (size_t)K + ((k0) + scol), BS_(b) + (w * 32 + 16) * 32); \
} while (0)

template<int EPI>
__global__ __launch_bounds__(256) void mgemm128_k(
    const ushort* __restrict__ A, const ushort* __restrict__ W,
    const float* __restrict__ bias, float* __restrict__ Cf,
    ushort* __restrict__ Cb, int M, int N, int K)
{
    __shared__ ushort shmem[16384];
    const int tid = threadIdx.x;
    const int lane = tid & 63;
    const int w = tid >> 6;
    const int wr = w >> 1, wc = w & 1;
    const int lr = lane & 15, lk = lane >> 4;
    const int bm = blockIdx.x * 128, bn = blockIdx.y * 128;
    const int srow = lane >> 2;
    const int scol = (((lane & 3) ^ ((srow >> 1) & 3)) * 8);

    f32x4 acc[4][4] = {};
    const int nt = K >> 5;

    STAGE128(0, 0);
    asm volatile("s_waitcnt vmcnt(0)" ::: "memory");
    __builtin_amdgcn_s_barrier();

    int cur = 0;
    for (int t = 0; t < nt; ++t) {
        if (t + 1 < nt) { STAGE128(cur ^ 1, (t + 1) * 32); }
        bf16x8 af[4], bfr[4];
        #pragma unroll
        for (int m = 0; m < 4; ++m) {
            int rr = wr * 64 + m * 16 + lr;
            af[m] = *reinterpret_cast<const bf16x8*>(&AS_(cur)[rr * 32 + ((lk ^ ((rr >> 1) & 3)) * 8)]);
        }
        #pragma unroll
        for (int n = 0; n < 4; ++n) {
            int rr = wc * 64 + n * 16 + lr;
            bfr[n] = *reinterpret_cast<const bf16x8*>(&BS_(cur)[rr * 32 + ((lk ^ ((rr >> 1) & 3)) * 8)]);
        }
        #pragma unroll
        for (int m = 0; m < 4; ++m)
            #pragma unroll
            for (int n = 0; n < 4; ++n)
                acc[m][n] = __builtin_amdgcn_mfma_f32_16x16x32_bf16(af[m], bfr[n], acc[m][n], 0, 0, 0);
        asm volatile("s_waitcnt vmcnt(0)" ::: "memory");
        __builtin_amdgcn_s_barrier();
        cur ^= 1;
    }

    #pragma unroll
    for (int n = 0; n < 4; ++n) {
        int col = bn + wc * 64 + n * 16 + lr;
        if (col >= N) continue;
        float bsv = bias ? bias[col] : 0.0f;
        #pragma unroll
        for (int m = 0; m < 4; ++m) {
            #pragma unroll
            for (int r4 = 0; r4 < 4; ++r4) {
                int row = bm + wr * 64 + m * 16 + lk * 4 + r4;
                float o = acc[m][n][r4] + bsv;
                size_t idx = (size_t)row * N + col;
                if (EPI == 1) Cb[idx] = f2b(gelu_exact(o));
                else          Cb[idx] = f2b(o);
            }
        }
    }
}

// ---------------------------------------------------------------------------
// lm_head kernel: 256x128 tile, 8 waves, 512 threads. 2-phase pipeline.
// Coalesced nontemporal f32 epilogue.
// ---------------------------------------------------------------------------
#define AS2_(b) (shmem + (b) * 8192)
#define BS2_(b) (shmem + 16384 + (b) * 4096)
#define STAGE256(b, k0) do { \
    GLOAD16(A + (size_t)(bm + w * 32 + srow) * (size_t)K + ((k0) + scol), AS2_(b) + (w * 32) * 32); \
    GLOAD16(A + (size_t)(bm + w * 32 + 16 + srow) * (size_t)K + ((k0) + scol), AS2_(b) + (w * 32 + 16) * 32); \
    int rb_ = bn + w * 16 + srow; if (rb_ > N - 1) rb_ = N - 1; \
    GLOAD16(W + (size_t)rb_ * (size_t)K + ((k0) + scol), BS2_(b) + (w * 16) * 32); \
} while (0)

__global__ __launch_bounds__(512) void mgemm256nt_k(
    const ushort* __restrict__ A, const ushort* __restrict__ W,
    float* __restrict__ Cf, int M, int N, int K)
{
    __shared__ ushort shmem[24576];
    const int tid = threadIdx.x;
    const int lane = tid & 63;
    const int w = tid >> 6;
    const int wr = w >> 1, wc = w & 1;
    const int lr = lane & 15, lk = lane >> 4;
    const int bm = blockIdx.x * 256, bn = blockIdx.y * 128;
    const int srow = lane >> 2;
    const int scol = (((lane & 3) ^ ((srow >> 1) & 3)) * 8);

    f32x4 acc[4][4] = {};
    const int nt = K >> 5;

    STAGE256(0, 0);
    asm volatile("s_waitcnt vmcnt(0)" ::: "memory");
    __builtin_amdgcn_s_barrier();

    int cur = 0;
    for (int t = 0; t < nt; ++t) {
        if (t + 1 < nt) { STAGE256(cur ^ 1, (t + 1) * 32); }
        bf16x8 af[4], bfr[4];
        #pragma unroll
        for (int m = 0; m < 4; ++m) {
            int rr = wr * 64 + m * 16 + lr;
            af[m] = *reinterpret_cast<const bf16x8*>(&AS2_(cur)[rr * 32 + ((lk ^ ((rr >> 1) & 3)) * 8)]);
        }
        #pragma unroll
        for (int n = 0; n < 4; ++n) {
            int rr = wc * 64 + n * 16 + lr;
            bfr[n] = *reinterpret_cast<const bf16x8*>(&BS2_(cur)[rr * 32 + ((lk ^ ((rr >> 1) & 3)) * 8)]);
        }
        #pragma unroll
        for (int m = 0; m < 4; ++m)
            #pragma unroll
            for (int n = 0; n < 4; ++n)
                acc[m][n] = __builtin_amdgcn_mfma_f32_16x16x32_bf16(af[m], bfr[n], acc[m][n], 0, 0, 0);
        asm volatile("s_waitcnt vmcnt(0)" ::: "memory");
        __builtin_amdgcn_s_barrier();
        cur ^= 1;
    }

    float* lds_f = (float*)shmem;
    const int wbase = w * (16 * 68);
    #pragma unroll
    for (int m = 0; m < 4; ++m) {
        #pragma unroll
        for (int n = 0; n < 4; ++n) {
            #pragma unroll
            for (int r4 = 0; r4 < 4; ++r4)
                lds_f[wbase + (lk * 4 + r4) * 68 + n * 16 + lr] = acc[m][n][r4];
        }
        __syncthreads();
        #pragma unroll
        for (int r = 0; r < 16; ++r) {
            int row = bm + wr * 64 + m * 16 + r;
            int col = bn + wc * 64 + lane;
            float v = lds_f[wbase + r * 68 + lane];
            if (col < N)
                __builtin_nontemporal_store(v, &Cf[(size_t)row * N + col]);
        }
        __syncthreads();
    }
}

// ---------------------------------------------------------------------------
// 128x64 tile, 4 waves. 2-phase pipeline. gelu->bf16. Used by gp1 + fc1.
// ---------------------------------------------------------------------------
#define STAGE12864(b, k0) do { \
    GLOAD16(A + (size_t)(bm + w * 16 + srow) * (size_t)K + ((k0) + scol), &As[b][(w * 16) * 32]); \
    GLOAD16(A + (size_t)(bm + 64 + w * 16 + srow) * (size_t)K + ((k0) + scol), &As[b][(64 + w * 16) * 32]); \
    GLOAD16(W + (size_t)(bn + w * 16 + srow) * (size_t)K + ((k0) + scol), &Bs[b][(w * 16) * 32]); \
} while (0)

__global__ __launch_bounds__(256) void mgemm12864_k(
    const ushort* __restrict__ A, const ushort* __restrict__ W,
    const float* __restrict__ bias, ushort* __restrict__ ub,
    int M, int N, int K)
{
    __shared__ ushort As[2][128 * 32];
    __shared__ ushort Bs[2][64 * 32];
    const int tid = threadIdx.x;
    const int lane = tid & 63;
    const int w = tid >> 6;
    const int wr = w >> 1, wc = w & 1;
    const int lr = lane & 15, lk = lane >> 4;
    const int bm = blockIdx.x * 128, bn = blockIdx.y * 64;
    const int srow = lane >> 2;
    const int scol = (((lane & 3) ^ ((srow >> 1) & 3)) * 8);

    f32x4 acc[4][2] = {};
    const int nt = K >> 5;

    STAGE12864(0, 0);
    asm volatile("s_waitcnt vmcnt(0)" ::: "memory");
    __builtin_amdgcn_s_barrier();

    int cur = 0;
    for (int t = 0; t < nt; ++t) {
        if (t + 1 < nt) { STAGE12864(cur ^ 1, (t + 1) * 32); }
        bf16x8 af[4], bfr[2];
        #pragma unroll
        for (int m = 0; m < 4; ++m) {
            int rr = wr * 64 + m * 16 + lr;
            af[m] = *reinterpret_cast<const bf16x8*>(&As[cur][rr * 32 + ((lk ^ ((rr >> 1) & 3)) * 8)]);
        }
        #pragma unroll
        for (int n = 0; n < 2; ++n) {
            int rr = wc * 32 + n * 16 + lr;
            bfr[n] = *reinterpret_cast<const bf16x8*>(&Bs[cur][rr * 32 + ((lk ^ ((rr >> 1) & 3)) * 8)]);
        }
        #pragma unroll
        for (int m = 0; m < 4; ++m)
            #pragma unroll
            for (int n = 0; n < 2; ++n)
                acc[m][n] = __builtin_amdgcn_mfma_f32_16x16x32_bf16(af[m], bfr[n], acc[m][n], 0, 0, 0);
        asm volatile("s_waitcnt vmcnt(0)" ::: "memory");
        __builtin_amdgcn_s_barrier();
        cur ^= 1;
    }

    #pragma unroll
    for (int n = 0; n < 2; ++n) {
        int col = bn + wc * 32 + n * 16 + lr;
        if (col >= N) continue;
        float bsv = bias ? bias[col] : 0.0f;
        #pragma unroll
        for (int m = 0; m < 4; ++m) {
            #pragma unroll
            for (int r4 = 0; r4 < 4; ++r4) {
                int row = bm + wr * 64 + m * 16 + lk * 4 + r4;
                float o = acc[m][n][r4] + bsv;
                ub[(size_t)row * N + col] = f2b(gelu_exact(o));
            }
        }
    }
}

// ---------------------------------------------------------------------------
// 64x64 tile, 4 waves (2x2), 2-phase pipeline. (gate, fc2)
// EPI==2: alpha=sigmoid(o); x += a*h + (1-a)*g, h/g read from bf16 hg.
// EPI==3: Cf += o (fc2).
// ---------------------------------------------------------------------------
#define STAGE64(b, k0) do { \
    GLOAD16(A + (size_t)(bm + w * 16 + srow) * (size_t)K + ((k0) + scol), &As[b][(w * 16) * 32]); \
    GLOAD16(W + (size_t)(bn + w * 16 + srow) * (size_t)K + ((k0) + scol), &Bs[b][(w * 16) * 32]); \
} while (0)

template<int EPI>
__global__ __launch_bounds__(256) void mgemm64_k(
    const ushort* __restrict__ A, const ushort* __restrict__ W,
    const float* __restrict__ bias, float* __restrict__ Cf,
    const ushort* __restrict__ hg, ushort* __restrict__ ub,
    int M, int N, int K)
{
    __shared__ ushort As[2][64 * 32];
    __shared__ ushort Bs[2][64 * 32];
    const int tid = threadIdx.x;
    const int lane = tid & 63;
    const int w = tid >> 6;
    const int wr = w >> 1, wc = w & 1;
    const int lr = lane & 15, lk = lane >> 4;
    const int bm = blockIdx.x * 64, bn = blockIdx.y * 64;
    const int srow = lane >> 2;
    const int scol = (((lane & 3) ^ ((srow >> 1) & 3)) * 8);

    f32x4 acc[2][2] = {};
    const int nt = K >> 5;

    STAGE64(0, 0);
    asm volatile("s_waitcnt vmcnt(0)" ::: "memory");
    __builtin_amdgcn_s_barrier();

    int cur = 0;
    for (int t = 0; t < nt; ++t) {
        if (t + 1 < nt) { STAGE64(cur ^ 1, (t + 1) * 32); }
        bf16x8 af[2], bfr[2];
        #pragma unroll
        for (int m = 0; m < 2; ++m) {
            int rr = wr * 32 + m * 16 + lr;
            af[m] = *reinterpret_cast<const bf16x8*>(&As[cur][rr * 32 + ((lk ^ ((rr >> 1) & 3)) * 8)]);
        }
        #pragma unroll
        for (int n = 0; n < 2; ++n) {
            int rr = wc * 32 + n * 16 + lr;
            bfr[n] = *reinterpret_cast<const bf16x8*>(&Bs[cur][rr * 32 + ((lk ^ ((rr >> 1) & 3)) * 8)]);
        }
        #pragma unroll
        for (int m = 0; m < 2; ++m)
            #pragma unroll
            for (int n = 0; n < 2; ++n)
                acc[m][n] = __builtin_amdgcn_mfma_f32_16x16x32_bf16(af[m], bfr[n], acc[m][n], 0, 0, 0);
        asm volatile("s_waitcnt vmcnt(0)" ::: "memory");
        __builtin_amdgcn_s_barrier();
        cur ^= 1;
    }

    #pragma unroll
    for (int n = 0; n < 2; ++n) {
        int col = bn + wc * 32 + n * 16 + lr;
        if (col >= N) continue;
        float bsv = bias ? bias[col] : 0.0f;
        #pragma unroll
        for (int m = 0; m < 2; ++m) {
            #pragma unroll
            for (int r4 = 0; r4 < 4; ++r4) {
                int row = bm + wr * 32 + m * 16 + lk * 4 + r4;
                float o = acc[m][n][r4] + bsv;
                size_t idx = (size_t)row * N + col;
                if (EPI == 2) {
                    float a = sigmoid_f(o);
                    float hv = b2f(hg[(size_t)row * (2 * D_) + col]);
                    float gv = b2f(hg[(size_t)row * (2 * D_) + D_ + col]);
                    Cf[idx] = Cf[idx] + a * hv + (1.0f - a) * gv;
                } else {
                    Cf[idx] += o;
                }
            }
        }
    }
}

// ---------------------------------------------------------------------------
// gp2 with credsum FOLDED into A-staging (R17): A-tile = masked per-row
// average over the 7 c1b delta slices, reduced in f32 regs, ds_write'd to
// the swizzled LDS slot. B staged via GLOAD16 as usual. __syncthreads()
// provides the full vmcnt+lgkm drain each step (compiler-emitted; covers
// both the B-DMA and the A ds_writes). K = DG = 256 -> 8 steps.
// Epilogue: g bf16 into hg[., D+col]; l==0 rows forced to 0 (count==0).
// ---------------------------------------------------------------------------
__global__ __launch_bounds__(256) void gp2fused_k(
    const ushort* __restrict__ c1b, const ushort* __restrict__ W,
    const float* __restrict__ bias, ushort* __restrict__ hg)
{
    __shared__ ushort As[2][64 * 32];
    __shared__ ushort Bs[2][64 * 32];
    const int tid = threadIdx.x;
    const int lane = tid & 63;
    const int w = tid >> 6;
    const int wr = w >> 1, wc = w & 1;
    const int lr = lane & 15, lk = lane >> 4;
    const int bm = blockIdx.x * 64, bn = blockIdx.y * 64;
    const int srow = lane >> 2;          // 0..15
    const int scolc = lane & 3;          // A chunk 0..3 (16B each)
    const int scol = ((scolc ^ ((srow >> 1) & 3)) * 8);  // B swizzled source

    const int arow = w * 16 + srow;      // 0..63 within tile
    const int grow = bm + arow;
    const int al = grow & (L_ - 1);
    const int adc = scolc ^ ((arow >> 1) & 3);   // swizzled A dest chunk
    int acnt = 0;
    #pragma unroll
    for (int oi = 0; oi < 7; ++oi) acnt += (al >= (1 << oi));
    const float ainv = 1.0f / (float)(acnt > 0 ? acnt : 1);

    f32x4 acc[2][2] = {};
    const int nt = DG_ >> 5;   // 8

    // A staging: masked f32 average of 7 slices -> bf16 -> swizzled ds_write
    #define GP2_STAGE_A(b, k0) do { \
        float s_[8] = {0.f,0.f,0.f,0.f,0.f,0.f,0.f,0.f}; \
        _Pragma("unroll") \
        for (int oi_ = 0; oi_ < 7; ++oi_) { \
            if (al >= (1 << oi_)) { \
                uint4 v_ = *reinterpret_cast<const uint4*>( \
                    c1b + ((size_t)oi_ * M_ + grow) * DG_ + (k0) + scolc * 8); \
                const ushort* u_ = (const ushort*)&v_; \
                _Pragma("unroll") \
                for (int e_ = 0; e_ < 8; ++e_) s_[e_] += b2f(u_[e_]); \
            } \
        } \
        ushort o_[8]; \
        _Pragma("unroll") \
        for (int e_ = 0; e_ < 8; ++e_) o_[e_] = f2b(s_[e_] * ainv); \
        *reinterpret_cast<uint4*>(&As[b][arow * 32 + adc * 8]) = \
            *reinterpret_cast<const uint4*>(o_); \
    } while (0)

    GP2_STAGE_A(0, 0);
    GLOAD16(W + (size_t)(bn + w * 16 + srow) * DG_ + scol, &Bs[0][(w * 16) * 32]);
    __syncthreads();

    int cur = 0;
    for (int t = 0; t < nt; ++t) {
        if (t + 1 < nt) {
            GP2_STAGE_A(cur ^ 1, (t + 1) * 32);
            GLOAD16(W + (size_t)(bn + w * 16 + srow) * DG_ + ((t + 1) * 32 + scol),
                    &Bs[cur ^ 1][(w * 16) * 32]);
        }
        bf16x8 af[2], bfr[2];
        #pragma unroll
        for (int m = 0; m < 2; ++m) {
            int rr = wr * 32 + m * 16 + lr;
            af[m] = *reinterpret_cast<const bf16x8*>(&As[cur][rr * 32 + ((lk ^ ((rr >> 1) & 3)) * 8)]);
        }
        #pragma unroll
        for (int n = 0; n < 2; ++n) {
            int rr = wc * 32 + n * 16 + lr;
            bfr[n] = *reinterpret_cast<const bf16x8*>(&Bs[cur][rr * 32 + ((lk ^ ((rr >> 1) & 3)) * 8)]);
        }
        #pragma unroll
        for (int m = 0; m < 2; ++m)
            #pragma unroll
            for (int n = 0; n < 2; ++n)
                acc[m][n] = __builtin_amdgcn_mfma_f32_16x16x32_bf16(af[m], bfr[n], acc[m][n], 0, 0, 0);
        __syncthreads();
        cur ^= 1;
    }
    #undef GP2_STAGE_A

    #pragma unroll
    for (int n = 0; n < 2; ++n) {
        int col = bn + wc * 32 + n * 16 + lr;
        float bsv = bias[col];
        #pragma unroll
        for (int m = 0; m < 2; ++m) {
            #pragma unroll
            for (int r4 = 0; r4 < 4; ++r4) {
                int row = bm + wr * 32 + m * 16 + lk * 4 + r4;
                float o = acc[m][n][r4] + bsv;
                if ((row & (L_ - 1)) == 0) o = 0.0f;   // count==0 rows: g = 0
                hg[(size_t)row * (2 * D_) + D_ + col] = f2b(o);
            }
        }
    }
}

// ---------------------------------------------------------------------------
// Fused LN1 + red projection: one block (128 thr) per row.
// ---------------------------------------------------------------------------
__global__ __launch_bounds__(128) void lnred_k(
    const float* __restrict__ x, const float* __restrict__ w,
    const float* __restrict__ b, const float* __restrict__ rw,
    const float* __restrict__ rb, ushort* __restrict__ hgb,
    float* __restrict__ z)
{
    int row = blockIdx.x;
    int tid = threadIdx.x;
    const float* xr = x + (size_t)row * D_;
    __shared__ float hrow[D_];
    __shared__ float parts[R_][5];
    float v[5];
    float sum = 0.f, sumsq = 0.f;
    #pragma unroll
    for (int t = 0; t < 5; ++t) {
        v[t] = xr[tid + t * 128];
        sum += v[t]; sumsq += v[t] * v[t];
    }
    #pragma unroll
    for (int off = 32; off > 0; off >>= 1) {
        sum += __shfl_down(sum, off);
        sumsq += __shfl_down(sumsq, off);
    }
    __shared__ float s0[2], s1[2];
    if ((tid & 63) == 0) { s0[tid >> 6] = sum; s1[tid >> 6] = sumsq; }
    __syncthreads();
    float m = (s0[0] + s0[1]) * (1.0f / D_);
    float var = (s1[0] + s1[1]) * (1.0f / D_) - m * m;
    float inv = rsqrtf(var + LN_EPS_);
    #pragma unroll
    for (int t = 0; t < 5; ++t) {
        int d = tid + t * 128;
        float o = (v[t] - m) * inv * w[d] + b[d];
        hgb[(size_t)row * (2 * D_) + d] = f2b(o);
        hrow[d] = o;
    }
    __syncthreads();
    if (tid < 120) {
        int c = tid / 5, ch = tid - c * 5;
        const float4* hv = (const float4*)(hrow + ch * 128);
        const float4* wv = (const float4*)(rw + (size_t)c * D_ + ch * 128);
        float p = 0.f;
        #pragma unroll 8
        for (int k = 0; k < 32; ++k) {
            float4 a = hv[k], bb = wv[k];
            p += a.x * bb.x + a.y * bb.y + a.z * bb.z + a.w * bb.w;
        }
        parts[c][ch] = p;
    }
    __syncthreads();
    if (tid < R_) {
        float s = parts[tid][0] + parts[tid][1] + parts[tid][2] + parts[tid][3] + parts[tid][4];
        z[(size_t)row * R_ + tid] = s + rb[tid];
    }
}

// ---------------------------------------------------------------------------
// Plucker, all 7 deltas in one block per row.
// ---------------------------------------------------------------------------
__global__ __launch_bounds__(128) void plucker_all_k(
    const float* __restrict__ z, ushort* __restrict__ pb)
{
    int row = blockIdx.x;
    int l = row & (L_ - 1);
    int tid = threadIdx.x;
    __shared__ float zc[R_], zp[R_];
    __shared__ float wsum[2];
    if (tid < R_) zc[tid] = z[(size_t)row * R_ + tid];
    for (int oi = 0; oi < 7; ++oi) {
        int delta = 1 << oi;
        ushort* out = pb + ((size_t)oi * M_ + row) * PLUP_;
        if (l < delta) {
            __syncthreads();
            for (int idx = tid; idx < PLUP_; idx += 128) out[idx] = 0;
            __syncthreads();
            continue;
        }
        if (tid < R_) zp[tid] = z[(size_t)(row - delta) * R_ + tid];
        __syncthreads();
        float vals[3];
        float ss = 0.f;
        #pragma unroll
        for (int t = 0; t < 3; ++t) {
            int idx = tid + t * 128;
            float val = 0.f;
            if (idx < PLU_) {
                int i = 0, rem = idx;
                while (rem >= 23 - i) { rem -= 23 - i; ++i; }
                int j = i + 1 + rem;
                val = zp[i] * zc[j] - zp[j] * zc[i];
            }
            vals[t] = val;
            ss += val * val;
        }
        #pragma unroll
        for (int off = 32; off > 0; off >>= 1) ss += __shfl_down(ss, off);
        if ((tid & 63) == 0) wsum[tid >> 6] = ss;
        __syncthreads();
        float inv = 1.0f / fmaxf(sqrtf(wsum[0] + wsum[1]), EPS_);
        #pragma unroll
        for (int t = 0; t < 3; ++t) {
            int idx = tid + t * 128;
            if (idx < PLUP_) out[idx] = (idx < PLU_) ? f2b(vals[t] * inv) : (ushort)0;
        }
        __syncthreads();
    }
}

// ---------------------------------------------------------------------------
__global__ __launch_bounds__(256) void embed_k(
    const int* __restrict__ ids, const float* __restrict__ tok,
    const float* __restrict__ pos, float* __restrict__ x)
{
    int idx4 = blockIdx.x * 256 + threadIdx.x;
    if (idx4 >= M_ * D_ / 4) return;
    int idx = idx4 * 4;
    int row = idx / D_;
    int d = idx - row * D_;
    int l = row & (L_ - 1);
    float4 t = *reinterpret_cast<const float4*>(tok + (size_t)ids[row] * D_ + d);
    float4 p = *reinterpret_cast<const float4*>(pos + (size_t)l * D_ + d);
    float4 o = make_float4(t.x + p.x, t.y + p.y, t.z + p.z, t.w + p.w);
    *reinterpret_cast<float4*>(x + idx) = o;
}

__global__ __launch_bounds__(256) void cvt_k(
    const float* __restrict__ src, ushort* __restrict__ dst, int n4)
{
    int idx4 = blockIdx.x * 256 + threadIdx.x;
    if (idx4 >= n4) return;
    float4 v = *reinterpret_cast<const float4*>(src + idx4 * 4);
    *reinterpret_cast<ushort4*>(dst + idx4 * 4) = f4b4(v);
}

// per-layer weight conversion (gp1 padded 276->288, gp2, gate, fc1, fc2)
#define WC_G1  73728
#define WC_G2  (WC_G1 + 163840)
#define WC_GT  (WC_G2 + 819200)
#define WC_F1  (WC_GT + 1638400)
#define WC_F2  (WC_F1 + 1638400)
__global__ __launch_bounds__(256) void wconv_all_k(
    const float* __restrict__ g1, const float* __restrict__ g2,
    const float* __restrict__ gt, const float* __restrict__ f1,
    const float* __restrict__ f2, ushort* __restrict__ wb_all)
{
    int l = blockIdx.y;
    int idx4 = blockIdx.x * 256 + threadIdx.x;
    int idx = idx4 * 4;
    if (idx >= WC_F2) return;
    ushort* wb = wb_all + (size_t)l * WC_F2;
    float4 v;
    if (idx < WC_G1) {
        const float* s = g1 + (size_t)l * DG_ * PLU_;
        int row = idx / PLUP_, c = idx - row * PLUP_;
        if (c < PLU_) v = *reinterpret_cast<const float4*>(s + (size_t)row * PLU_ + c);
        else          v = make_float4(0.f, 0.f, 0.f, 0.f);
    } else if (idx < WC_G2) {
        v = *reinterpret_cast<const float4*>(g2 + (size_t)l * D_ * DG_ + (idx - WC_G1));
    } else if (idx < WC_GT) {
        v = *reinterpret_cast<const float4*>(gt + (size_t)l * D_ * 2 * D_ + (idx - WC_G2));
    } else if (idx < WC_F1) {
        v = *reinterpret_cast<const float4*>(f1 + (size_t)l * DF_ * D_ + (idx - WC_GT));
    } else {
        v = *reinterpret_cast<const float4*>(f2 + (size_t)l * D_ * DF_ + (idx - WC_F1));
    }
    *reinterpret_cast<ushort4*>(wb + idx) = f4b4(v);
}

// ---------------------------------------------------------------------------
__global__ __launch_bounds__(128) void ln_k(
    const float* __restrict__ x, const float* __restrict__ w,
    const float* __restrict__ b, float* __restrict__ outf,
    ushort* __restrict__ outb, int bstride)
{
    int row = blockIdx.x;
    int tid = threadIdx.x;
    const float* xr = x + (size_t)row * D_;
    float v[5];
    float sum = 0.f, sumsq = 0.f;
    #pragma unroll
    for (int t = 0; t < 5; ++t) {
        v[t] = xr[tid + t * 128];
        sum += v[t]; sumsq += v[t] * v[t];
    }
    #pragma unroll
    for (int off = 32; off > 0; off >>= 1) {
        sum += __shfl_down(sum, off);
        sumsq += __shfl_down(sumsq, off);
    }
    __shared__ float s0[2], s1[2];
    if ((tid & 63) == 0) { s0[tid >> 6] = sum; s1[tid >> 6] = sumsq; }
    __syncthreads();
    float m = (s0[0] + s0[1]) * (1.0f / D_);
    float var = (s1[0] + s1[1]) * (1.0f / D_) - m * m;
    float inv = rsqrtf(var + LN_EPS_);
    #pragma unroll
    for (int t = 0; t < 5; ++t) {
        int d = tid + t * 128;
        float o = (v[t] - m) * inv * w[d] + b[d];
        if (outf) outf[(size_t)row * D_ + d] = o;
        if (outb) outb[(size_t)row * bstride + d] = f2b(o);
    }
}

// ---------------------------------------------------------------------------
static void mg64(int epi, const ushort* A, const ushort* W, const float* bias,
                 float* Cf, const ushort* hg, ushort* ub,
                 int M, int N, int K, hipStream_t s)
{
    dim3 grid(M / 64, N / 64), block(256);
    if (epi == 2) mgemm64_k<2><<<grid, block, 0, s>>>(A, W, bias, Cf, hg, ub, M, N, K);
    else          mgemm64_k<3><<<grid, block, 0, s>>>(A, W, bias, Cf, hg, ub, M, N, K);
}

extern "C" void kernel_launch(void* const* d_in, const int* in_sizes, int n_in,
                              void* d_out, int out_size, void* d_ws, size_t ws_size,
                              hipStream_t stream)
{
    const int*   ids   = (const int*)d_in[0];
    const float* tok   = (const float*)d_in[1];
    const float* pos   = (const float*)d_in[2];
    const float* ln1w  = (const float*)d_in[3];
    const float* ln1b  = (const float*)d_in[4];
    const float* redw  = (const float*)d_in[5];
    const float* redb  = (const float*)d_in[6];
    const float* gp1w  = (const float*)d_in[7];
    const float* gp1b  = (const float*)d_in[8];
    const float* gp2w  = (const float*)d_in[9];
    const float* gp2b  = (const float*)d_in[10];
    const float* gatew = (const float*)d_in[11];
    const float* gateb = (const float*)d_in[12];
    const float* ln2w  = (const float*)d_in[13];
    const float* ln2b  = (const float*)d_in[14];
    const float* fc1w  = (const float*)d_in[15];
    const float* fc1b  = (const float*)d_in[16];
    const float* fc2w  = (const float*)d_in[17];
    const float* fc2b  = (const float*)d_in[18];
    const float* fnw   = (const float*)d_in[19];
    const float* fnb   = (const float*)d_in[20];
    float* out = (float*)d_out;

    const size_t MD = (size_t)M_ * D_;
    float* ws = (float*)d_ws;
    float* x = ws;                       // MD f32
    float* z = x + MD;                   // M_*R_ f32
    ushort* pb    = (ushort*)(z + (size_t)M_ * R_);       // 7*M_*288
    ushort* c1b   = pb + (size_t)7 * M_ * PLUP_;          // 7*M_*256
    ushort* hgb   = c1b + (size_t)7 * M_ * DG_;           // M_*1280
    ushort* h2b   = hgb + (size_t)M_ * 2 * D_;            // M_*640
    ushort* ffb   = h2b + MD;                             // M_*2560
    ushort* xnb   = ffb + (size_t)M_ * DF_;               // M_*640
    ushort* tokb  = xnb + MD;                             // V_*640
    ushort* wb    = tokb + (size_t)V_ * D_;               // WC_F2 (or x16)

    const size_t base_bytes = (size_t)((char*)wb - (char*)d_ws);
    const bool all_w = ws_size >= base_bytes + (size_t)NL_ * WC_F2 * 2;

    const int WC_GRID4 = (WC_F2 / 4 + 255) / 256;

    embed_k<<<(M_ * D_ / 4 + 255) / 256, 256, 0, stream>>>(ids, tok, pos, x);
    cvt_k<<<(V_ * D_ / 4 + 255) / 256, 256, 0, stream>>>(tok, tokb, V_ * D_ / 4);
    if (all_w)
        wconv_all_k<<<dim3(WC_GRID4, NL_), 256, 0, stream>>>(gp1w, gp2w, gatew, fc1w, fc2w, wb);

    for (int l = 0; l < NL_; ++l) {
        const ushort* wbl = all_w ? wb + (size_t)l * WC_F2 : wb;
        if (!all_w)
            wconv_all_k<<<dim3(WC_GRID4, 1), 256, 0, stream>>>(
                gp1w + (size_t)l * DG_ * PLU_, gp2w + (size_t)l * D_ * DG_,
                gatew + (size_t)l * D_ * 2 * D_, fc1w + (size_t)l * DF_ * D_,
                fc2w + (size_t)l * D_ * DF_, wb);
        lnred_k<<<M_, 128, 0, stream>>>(x, ln1w + (size_t)l * D_, ln1b + (size_t)l * D_,
                                        redw + (size_t)l * R_ * D_, redb + (size_t)l * R_,
                                        hgb, z);
        plucker_all_k<<<M_, 128, 0, stream>>>(z, pb);
        // gp1: 128x64 tile (896 blocks)
        {
            dim3 grid(7 * M_ / 128, DG_ / 64), block(256);
            mgemm12864_k<<<grid, block, 0, stream>>>(pb, wbl, gp1b + (size_t)l * DG_,
                                                     c1b, 7 * M_, DG_, PLUP_);
        }
        // gp2 + credsum fused (R17): masked 7-slice average in A-staging
        {
            dim3 grid(M_ / 64, D_ / 64), block(256);
            gp2fused_k<<<grid, block, 0, stream>>>(c1b, wbl + WC_G1,
                                                   gp2b + (size_t)l * D_, hgb);
        }
        // gate fused with x-update; h,g read from bf16 hgb; 640 blocks
        mg64(2, hgb, wbl + WC_G2, gateb + (size_t)l * D_, x, hgb, nullptr,
             M_, D_, 2 * D_, stream);
        ln_k<<<M_, 128, 0, stream>>>(x, ln2w + (size_t)l * D_, ln2b + (size_t)l * D_,
                                     nullptr, h2b, D_);
        // fc1: 128x64 tile (1280 blocks)
        {
            dim3 grid(M_ / 128, DF_ / 64), block(256);
            mgemm12864_k<<<grid, block, 0, stream>>>(h2b, wbl + WC_GT,
                                                     fc1b + (size_t)l * DF_,
                                                     ffb, M_, DF_, D_);
        }
        // fc2 accumulate into x; 640 blocks
        mg64(3, ffb, wbl + WC_F1, fc2b + (size_t)l * D_, x, nullptr, nullptr,
             M_, D_, DF_, stream);
    }
    ln_k<<<M_, 128, 0, stream>>>(x, fnw, fnb, nullptr, xnb, D_);
    {   // lm_head: 256x128 tile + 2-phase + nontemporal stores
        dim3 grid(M_ / 256, (V_ + 127) / 128), block(512);
        mgemm256nt_k<<<grid, block, 0, stream>>>(xnb, tokb, out, M_, V_, D_);
    }
}

// Round 18
// 3737.373 us; speedup vs baseline: 1.0310x; 1.0310x over previous
//
#include <hip/hip_runtime.h>
#include <cmath>

#define V_ 50257
#define D_ 640
#define NL_ 16
#define DF_ 2560
#define R_ 24
#define DG_ 256
#define PLU_ 276
#define PLUP_ 288
#define B_ 4
#define L_ 1024
#define M_ (B_*L_)
#define EPS_ 1e-6f
#define LN_EPS_ 1e-5f

typedef __bf16 bf16x8 __attribute__((ext_vector_type(8)));
typedef float f32x4 __attribute__((ext_vector_type(4)));

__device__ __forceinline__ float gelu_exact(float x) {
    return 0.5f * x * (1.0f + erff(x * 0.70710678118654752f));
}
__device__ __forceinline__ float sigmoid_f(float x) {
    return 1.0f / (1.0f + expf(-x));
}
__device__ __forceinline__ ushort f2b(float f) {
    union { float f; unsigned u; } v; v.f = f;
    unsigned u = v.u;
    return (ushort)((u + 0x7FFFu + ((u >> 16) & 1u)) >> 16);
}
__device__ __forceinline__ float b2f(ushort b) {
    union { unsigned u; float f; } v; v.u = ((unsigned)b) << 16;
    return v.f;
}
__device__ __forceinline__ ushort4 f4b4(float4 v) {
    ushort4 o;
    o.x = f2b(v.x); o.y = f2b(v.y); o.z = f2b(v.z); o.w = f2b(v.w);
    return o;
}

#define GLOAD16(gptr, lptr) \
    __builtin_amdgcn_global_load_lds((const __attribute__((address_space(1))) void*)(gptr), \
                                     (__attribute__((address_space(3))) void*)(lptr), 16, 0, 0)

// LEDGER:
// R4: XCD remap regressed (lm_head FETCH 288->830MB). Natural blockIdx order.
// R2->R3: LDS XOR-swizzle: SQ_LDS_BANK_CONFLICT 3.2e7 -> 0. Keep.
// R6,R9 (races) + R12,R13 (correct w/ lgkm-fence but SLOWER): 3-stage
//     counted-vmcnt pipelining CLOSED. Schedule is 2-phase:
//     {STAGE(next); ds_read+MFMA(cur); vmcnt(0); s_barrier}.
// R7: coalesced LDS-transpose f32 epilogue for lm_head. Keep.
// R8: gp2 linearity fusion (credsum before gp2, 7x FLOP cut): 4686->4191.
// R10: gate epilogue reads h/g from bf16 hgb: 4191->4079.
// R11: lm_head 256x128 + nontemporal stores: 4079->4047 (lm_head at ~90%
//     of the m97-structure ceiling for K=640; structural).
// R14: gp1 tail fix + vectorized wconv/cvt/embed + merged plucker: ->3972.
// R15: occupancy lever gate/fc2/gp2 -> 64x64 tiles: 3972->3785.
// R16: occupancy lever fc1 -> 128x64 (1280 blocks): 3785->3743. CHAMPION.
// R17: credsum-into-gp2 fusion REGRESSED (3853): folding a BW-bound
//     producer into a latency-bound consumer's staging path re-reads 7
//     slices through per-step drains. Fusion space around gp2 is mapped:
//     separate credsum is measured-better. REVERTED (this file == R16).

// ---------------------------------------------------------------------------
// 128x128 tile, 4 waves (2x2). 2-phase pipeline. EPI: 1 = gelu->bf16; 4 = bf16
// (retained; unused by default schedule)
// ---------------------------------------------------------------------------
#define AS_(b) (shmem + (b) * 4096)
#define BS_(b) (shmem + 8192 + (b) * 4096)
#define STAGE128(b, k0) do { \
    GLOAD16(A + (size_t)(bm + w * 32 + srow) * (size_t)K + ((k0) + scol), AS_(b) + (w * 32) * 32); \
    GLOAD16(A + (size_t)(bm + w * 32 + 16 + srow) * (size_t)K + ((k0) + scol), AS_(b) + (w * 32 + 16) * 32); \
    int rb0_ = bn + w * 32 + srow;      if (rb0_ > N - 1) rb0_ = N - 1; \
    int rb1_ = bn + w * 32 + 16 + srow; if (rb1_ > N - 1) rb1_ = N - 1; \
    GLOAD16(W + (size_t)rb0_ * (size_t)K + ((k0) + scol), BS_(b) + (w * 32) * 32); \
    GLOAD16(W + (size_t)rb1_ * (size_t)K + ((k0) + scol), BS_(b) + (w * 32 + 16) * 32); \
} while (0)

template<int EPI>
__global__ __launch_bounds__(256) void mgemm128_k(
    const ushort* __restrict__ A, const ushort* __restrict__ W,
    const float* __restrict__ bias, float* __restrict__ Cf,
    ushort* __restrict__ Cb, int M, int N, int K)
{
    __shared__ ushort shmem[16384];
    const int tid = threadIdx.x;
    const int lane = tid & 63;
    const int w = tid >> 6;
    const int wr = w >> 1, wc = w & 1;
    const int lr = lane & 15, lk = lane >> 4;
    const int bm = blockIdx.x * 128, bn = blockIdx.y * 128;
    const int srow = lane >> 2;
    const int scol = (((lane & 3) ^ ((srow >> 1) & 3)) * 8);

    f32x4 acc[4][4] = {};
    const int nt = K >> 5;

    STAGE128(0, 0);
    asm volatile("s_waitcnt vmcnt(0)" ::: "memory");
    __builtin_amdgcn_s_barrier();

    int cur = 0;
    for (int t = 0; t < nt; ++t) {
        if (t + 1 < nt) { STAGE128(cur ^ 1, (t + 1) * 32); }
        bf16x8 af[4], bfr[4];
        #pragma unroll
        for (int m = 0; m < 4; ++m) {
            int rr = wr * 64 + m * 16 + lr;
            af[m] = *reinterpret_cast<const bf16x8*>(&AS_(cur)[rr * 32 + ((lk ^ ((rr >> 1) & 3)) * 8)]);
        }
        #pragma unroll
        for (int n = 0; n < 4; ++n) {
            int rr = wc * 64 + n * 16 + lr;
            bfr[n] = *reinterpret_cast<const bf16x8*>(&BS_(cur)[rr * 32 + ((lk ^ ((rr >> 1) & 3)) * 8)]);
        }
        #pragma unroll
        for (int m = 0; m < 4; ++m)
            #pragma unroll
            for (int n = 0; n < 4; ++n)
                acc[m][n] = __builtin_amdgcn_mfma_f32_16x16x32_bf16(af[m], bfr[n], acc[m][n], 0, 0, 0);
        asm volatile("s_waitcnt vmcnt(0)" ::: "memory");
        __builtin_amdgcn_s_barrier();
        cur ^= 1;
    }

    #pragma unroll
    for (int n = 0; n < 4; ++n) {
        int col = bn + wc * 64 + n * 16 + lr;
        if (col >= N) continue;
        float bsv = bias ? bias[col] : 0.0f;
        #pragma unroll
        for (int m = 0; m < 4; ++m) {
            #pragma unroll
            for (int r4 = 0; r4 < 4; ++r4) {
                int row = bm + wr * 64 + m * 16 + lk * 4 + r4;
                float o = acc[m][n][r4] + bsv;
                size_t idx = (size_t)row * N + col;
                if (EPI == 1) Cb[idx] = f2b(gelu_exact(o));
                else          Cb[idx] = f2b(o);
            }
        }
    }
}

// ---------------------------------------------------------------------------
// lm_head kernel: 256x128 tile, 8 waves, 512 threads. 2-phase pipeline.
// Coalesced nontemporal f32 epilogue.
// ---------------------------------------------------------------------------
#define AS2_(b) (shmem + (b) * 8192)
#define BS2_(b) (shmem + 16384 + (b) * 4096)
#define STAGE256(b, k0) do { \
    GLOAD16(A + (size_t)(bm + w * 32 + srow) * (size_t)K + ((k0) + scol), AS2_(b) + (w * 32) * 32); \
    GLOAD16(A + (size_t)(bm + w * 32 + 16 + srow) * (size_t)K + ((k0) + scol), AS2_(b) + (w * 32 + 16) * 32); \
    int rb_ = bn + w * 16 + srow; if (rb_ > N - 1) rb_ = N - 1; \
    GLOAD16(W + (size_t)rb_ * (size_t)K + ((k0) + scol), BS2_(b) + (w * 16) * 32); \
} while (0)

__global__ __launch_bounds__(512) void mgemm256nt_k(
    const ushort* __restrict__ A, const ushort* __restrict__ W,
    float* __restrict__ Cf, int M, int N, int K)
{
    __shared__ ushort shmem[24576];
    const int tid = threadIdx.x;
    const int lane = tid & 63;
    const int w = tid >> 6;
    const int wr = w >> 1, wc = w & 1;
    const int lr = lane & 15, lk = lane >> 4;
    const int bm = blockIdx.x * 256, bn = blockIdx.y * 128;
    const int srow = lane >> 2;
    const int scol = (((lane & 3) ^ ((srow >> 1) & 3)) * 8);

    f32x4 acc[4][4] = {};
    const int nt = K >> 5;

    STAGE256(0, 0);
    asm volatile("s_waitcnt vmcnt(0)" ::: "memory");
    __builtin_amdgcn_s_barrier();

    int cur = 0;
    for (int t = 0; t < nt; ++t) {
        if (t + 1 < nt) { STAGE256(cur ^ 1, (t + 1) * 32); }
        bf16x8 af[4], bfr[4];
        #pragma unroll
        for (int m = 0; m < 4; ++m) {
            int rr = wr * 64 + m * 16 + lr;
            af[m] = *reinterpret_cast<const bf16x8*>(&AS2_(cur)[rr * 32 + ((lk ^ ((rr >> 1) & 3)) * 8)]);
        }
        #pragma unroll
        for (int n = 0; n < 4; ++n) {
            int rr = wc * 64 + n * 16 + lr;
            bfr[n] = *reinterpret_cast<const bf16x8*>(&BS2_(cur)[rr * 32 + ((lk ^ ((rr >> 1) & 3)) * 8)]);
        }
        #pragma unroll
        for (int m = 0; m < 4; ++m)
            #pragma unroll
            for (int n = 0; n < 4; ++n)
                acc[m][n] = __builtin_amdgcn_mfma_f32_16x16x32_bf16(af[m], bfr[n], acc[m][n], 0, 0, 0);
        asm volatile("s_waitcnt vmcnt(0)" ::: "memory");
        __builtin_amdgcn_s_barrier();
        cur ^= 1;
    }

    float* lds_f = (float*)shmem;
    const int wbase = w * (16 * 68);
    #pragma unroll
    for (int m = 0; m < 4; ++m) {
        #pragma unroll
        for (int n = 0; n < 4; ++n) {
            #pragma unroll
            for (int r4 = 0; r4 < 4; ++r4)
                lds_f[wbase + (lk * 4 + r4) * 68 + n * 16 + lr] = acc[m][n][r4];
        }
        __syncthreads();
        #pragma unroll
        for (int r = 0; r < 16; ++r) {
            int row = bm + wr * 64 + m * 16 + r;
            int col = bn + wc * 64 + lane;
            float v = lds_f[wbase + r * 68 + lane];
            if (col < N)
                __builtin_nontemporal_store(v, &Cf[(size_t)row * N + col]);
        }
        __syncthreads();
    }
}

// ---------------------------------------------------------------------------
// 128x64 tile, 4 waves. 2-phase pipeline. gelu->bf16. Used by gp1 + fc1.
// ---------------------------------------------------------------------------
#define STAGE12864(b, k0) do { \
    GLOAD16(A + (size_t)(bm + w * 16 + srow) * (size_t)K + ((k0) + scol), &As[b][(w * 16) * 32]); \
    GLOAD16(A + (size_t)(bm + 64 + w * 16 + srow) * (size_t)K + ((k0) + scol), &As[b][(64 + w * 16) * 32]); \
    GLOAD16(W + (size_t)(bn + w * 16 + srow) * (size_t)K + ((k0) + scol), &Bs[b][(w * 16) * 32]); \
} while (0)

__global__ __launch_bounds__(256) void mgemm12864_k(
    const ushort* __restrict__ A, const ushort* __restrict__ W,
    const float* __restrict__ bias, ushort* __restrict__ ub,
    int M, int N, int K)
{
    __shared__ ushort As[2][128 * 32];
    __shared__ ushort Bs[2][64 * 32];
    const int tid = threadIdx.x;
    const int lane = tid & 63;
    const int w = tid >> 6;
    const int wr = w >> 1, wc = w & 1;
    const int lr = lane & 15, lk = lane >> 4;
    const int bm = blockIdx.x * 128, bn = blockIdx.y * 64;
    const int srow = lane >> 2;
    const int scol = (((lane & 3) ^ ((srow >> 1) & 3)) * 8);

    f32x4 acc[4][2] = {};
    const int nt = K >> 5;

    STAGE12864(0, 0);
    asm volatile("s_waitcnt vmcnt(0)" ::: "memory");
    __builtin_amdgcn_s_barrier();

    int cur = 0;
    for (int t = 0; t < nt; ++t) {
        if (t + 1 < nt) { STAGE12864(cur ^ 1, (t + 1) * 32); }
        bf16x8 af[4], bfr[2];
        #pragma unroll
        for (int m = 0; m < 4; ++m) {
            int rr = wr * 64 + m * 16 + lr;
            af[m] = *reinterpret_cast<const bf16x8*>(&As[cur][rr * 32 + ((lk ^ ((rr >> 1) & 3)) * 8)]);
        }
        #pragma unroll
        for (int n = 0; n < 2; ++n) {
            int rr = wc * 32 + n * 16 + lr;
            bfr[n] = *reinterpret_cast<const bf16x8*>(&Bs[cur][rr * 32 + ((lk ^ ((rr >> 1) & 3)) * 8)]);
        }
        #pragma unroll
        for (int m = 0; m < 4; ++m)
            #pragma unroll
            for (int n = 0; n < 2; ++n)
                acc[m][n] = __builtin_amdgcn_mfma_f32_16x16x32_bf16(af[m], bfr[n], acc[m][n], 0, 0, 0);
        asm volatile("s_waitcnt vmcnt(0)" ::: "memory");
        __builtin_amdgcn_s_barrier();
        cur ^= 1;
    }

    #pragma unroll
    for (int n = 0; n < 2; ++n) {
        int col = bn + wc * 32 + n * 16 + lr;
        if (col >= N) continue;
        float bsv = bias ? bias[col] : 0.0f;
        #pragma unroll
        for (int m = 0; m < 4; ++m) {
            #pragma unroll
            for (int r4 = 0; r4 < 4; ++r4) {
                int row = bm + wr * 64 + m * 16 + lk * 4 + r4;
                float o = acc[m][n][r4] + bsv;
                ub[(size_t)row * N + col] = f2b(gelu_exact(o));
            }
        }
    }
}

// ---------------------------------------------------------------------------
// 64x64 tile, 4 waves (2x2), 2-phase pipeline. (gate, fc2, gp2)
// EPI==2: alpha=sigmoid(o); x += a*h + (1-a)*g, h/g read from bf16 hg.
// EPI==3: Cf += o (fc2).
// EPI==5: g-write after credsum: l==0 -> 0; bf16 into hg at D+col (gp2).
// ---------------------------------------------------------------------------
#define STAGE64(b, k0) do { \
    GLOAD16(A + (size_t)(bm + w * 16 + srow) * (size_t)K + ((k0) + scol), &As[b][(w * 16) * 32]); \
    GLOAD16(W + (size_t)(bn + w * 16 + srow) * (size_t)K + ((k0) + scol), &Bs[b][(w * 16) * 32]); \
} while (0)

template<int EPI>
__global__ __launch_bounds__(256) void mgemm64_k(
    const ushort* __restrict__ A, const ushort* __restrict__ W,
    const float* __restrict__ bias, float* __restrict__ Cf,
    const ushort* __restrict__ hg, ushort* __restrict__ ub,
    int M, int N, int K)
{
    __shared__ ushort As[2][64 * 32];
    __shared__ ushort Bs[2][64 * 32];
    const int tid = threadIdx.x;
    const int lane = tid & 63;
    const int w = tid >> 6;
    const int wr = w >> 1, wc = w & 1;
    const int lr = lane & 15, lk = lane >> 4;
    const int bm = blockIdx.x * 64, bn = blockIdx.y * 64;
    const int srow = lane >> 2;
    const int scol = (((lane & 3) ^ ((srow >> 1) & 3)) * 8);

    f32x4 acc[2][2] = {};
    const int nt = K >> 5;

    STAGE64(0, 0);
    asm volatile("s_waitcnt vmcnt(0)" ::: "memory");
    __builtin_amdgcn_s_barrier();

    int cur = 0;
    for (int t = 0; t < nt; ++t) {
        if (t + 1 < nt) { STAGE64(cur ^ 1, (t + 1) * 32); }
        bf16x8 af[2], bfr[2];
        #pragma unroll
        for (int m = 0; m < 2; ++m) {
            int rr = wr * 32 + m * 16 + lr;
            af[m] = *reinterpret_cast<const bf16x8*>(&As[cur][rr * 32 + ((lk ^ ((rr >> 1) & 3)) * 8)]);
        }
        #pragma unroll
        for (int n = 0; n < 2; ++n) {
            int rr = wc * 32 + n * 16 + lr;
            bfr[n] = *reinterpret_cast<const bf16x8*>(&Bs[cur][rr * 32 + ((lk ^ ((rr >> 1) & 3)) * 8)]);
        }
        #pragma unroll
        for (int m = 0; m < 2; ++m)
            #pragma unroll
            for (int n = 0; n < 2; ++n)
                acc[m][n] = __builtin_amdgcn_mfma_f32_16x16x32_bf16(af[m], bfr[n], acc[m][n], 0, 0, 0);
        asm volatile("s_waitcnt vmcnt(0)" ::: "memory");
        __builtin_amdgcn_s_barrier();
        cur ^= 1;
    }

    #pragma unroll
    for (int n = 0; n < 2; ++n) {
        int col = bn + wc * 32 + n * 16 + lr;
        if (col >= N) continue;
        float bsv = bias ? bias[col] : 0.0f;
        #pragma unroll
        for (int m = 0; m < 2; ++m) {
            #pragma unroll
            for (int r4 = 0; r4 < 4; ++r4) {
                int row = bm + wr * 32 + m * 16 + lk * 4 + r4;
                float o = acc[m][n][r4] + bsv;
                size_t idx = (size_t)row * N + col;
                if (EPI == 2) {
                    float a = sigmoid_f(o);
                    float hv = b2f(hg[(size_t)row * (2 * D_) + col]);
                    float gv = b2f(hg[(size_t)row * (2 * D_) + D_ + col]);
                    Cf[idx] = Cf[idx] + a * hv + (1.0f - a) * gv;
                } else if (EPI == 3) {
                    Cf[idx] += o;
                } else if (EPI == 5) {
                    if ((row & (L_ - 1)) == 0) o = 0.0f;   // count==0 rows: g = 0
                    ub[(size_t)row * (2 * D_) + D_ + col] = f2b(o);
                }
            }
        }
    }
}

// ---------------------------------------------------------------------------
// credsum: cravg[row, c] = (sum over valid deltas of c1[d,row,c]) / count.
// Standalone streaming kernel (R17 fusion measured-worse; keep separate).
// ---------------------------------------------------------------------------
__global__ __launch_bounds__(256) void credsum_k(
    const ushort* __restrict__ c1b, ushort* __restrict__ crb)
{
    int idx4 = blockIdx.x * 256 + threadIdx.x;
    if (idx4 >= M_ * DG_ / 4) return;
    int idx = idx4 * 4;
    int row = idx / DG_;
    int l = row & (L_ - 1);
    float s0 = 0.f, s1 = 0.f, s2 = 0.f, s3 = 0.f;
    int c = 0;
    #pragma unroll
    for (int oi = 0; oi < 7; ++oi) {
        if (l >= (1 << oi)) {
            ushort4 v = *reinterpret_cast<const ushort4*>(c1b + (size_t)oi * M_ * DG_ + idx);
            s0 += b2f(v.x); s1 += b2f(v.y); s2 += b2f(v.z); s3 += b2f(v.w);
            ++c;
        }
    }
    float inv = 1.0f / (float)max(c, 1);
    ushort4 o;
    o.x = f2b(s0 * inv); o.y = f2b(s1 * inv); o.z = f2b(s2 * inv); o.w = f2b(s3 * inv);
    *reinterpret_cast<ushort4*>(crb + idx) = o;
}

// ---------------------------------------------------------------------------
// Fused LN1 + red projection: one block (128 thr) per row.
// ---------------------------------------------------------------------------
__global__ __launch_bounds__(128) void lnred_k(
    const float* __restrict__ x, const float* __restrict__ w,
    const float* __restrict__ b, const float* __restrict__ rw,
    const float* __restrict__ rb, ushort* __restrict__ hgb,
    float* __restrict__ z)
{
    int row = blockIdx.x;
    int tid = threadIdx.x;
    const float* xr = x + (size_t)row * D_;
    __shared__ float hrow[D_];
    __shared__ float parts[R_][5];
    float v[5];
    float sum = 0.f, sumsq = 0.f;
    #pragma unroll
    for (int t = 0; t < 5; ++t) {
        v[t] = xr[tid + t * 128];
        sum += v[t]; sumsq += v[t] * v[t];
    }
    #pragma unroll
    for (int off = 32; off > 0; off >>= 1) {
        sum += __shfl_down(sum, off);
        sumsq += __shfl_down(sumsq, off);
    }
    __shared__ float s0[2], s1[2];
    if ((tid & 63) == 0) { s0[tid >> 6] = sum; s1[tid >> 6] = sumsq; }
    __syncthreads();
    float m = (s0[0] + s0[1]) * (1.0f / D_);
    float var = (s1[0] + s1[1]) * (1.0f / D_) - m * m;
    float inv = rsqrtf(var + LN_EPS_);
    #pragma unroll
    for (int t = 0; t < 5; ++t) {
        int d = tid + t * 128;
        float o = (v[t] - m) * inv * w[d] + b[d];
        hgb[(size_t)row * (2 * D_) + d] = f2b(o);
        hrow[d] = o;
    }
    __syncthreads();
    if (tid < 120) {
        int c = tid / 5, ch = tid - c * 5;
        const float4* hv = (const float4*)(hrow + ch * 128);
        const float4* wv = (const float4*)(rw + (size_t)c * D_ + ch * 128);
        float p = 0.f;
        #pragma unroll 8
        for (int k = 0; k < 32; ++k) {
            float4 a = hv[k], bb = wv[k];
            p += a.x * bb.x + a.y * bb.y + a.z * bb.z + a.w * bb.w;
        }
        parts[c][ch] = p;
    }
    __syncthreads();
    if (tid < R_) {
        float s = parts[tid][0] + parts[tid][1] + parts[tid][2] + parts[tid][3] + parts[tid][4];
        z[(size_t)row * R_ + tid] = s + rb[tid];
    }
}

// ---------------------------------------------------------------------------
// Plucker, all 7 deltas in one block per row.
// ---------------------------------------------------------------------------
__global__ __launch_bounds__(128) void plucker_all_k(
    const float* __restrict__ z, ushort* __restrict__ pb)
{
    int row = blockIdx.x;
    int l = row & (L_ - 1);
    int tid = threadIdx.x;
    __shared__ float zc[R_], zp[R_];
    __shared__ float wsum[2];
    if (tid < R_) zc[tid] = z[(size_t)row * R_ + tid];
    for (int oi = 0; oi < 7; ++oi) {
        int delta = 1 << oi;
        ushort* out = pb + ((size_t)oi * M_ + row) * PLUP_;
        if (l < delta) {
            __syncthreads();
            for (int idx = tid; idx < PLUP_; idx += 128) out[idx] = 0;
            __syncthreads();
            continue;
        }
        if (tid < R_) zp[tid] = z[(size_t)(row - delta) * R_ + tid];
        __syncthreads();
        float vals[3];
        float ss = 0.f;
        #pragma unroll
        for (int t = 0; t < 3; ++t) {
            int idx = tid + t * 128;
            float val = 0.f;
            if (idx < PLU_) {
                int i = 0, rem = idx;
                while (rem >= 23 - i) { rem -= 23 - i; ++i; }
                int j = i + 1 + rem;
                val = zp[i] * zc[j] - zp[j] * zc[i];
            }
            vals[t] = val;
            ss += val * val;
        }
        #pragma unroll
        for (int off = 32; off > 0; off >>= 1) ss += __shfl_down(ss, off);
        if ((tid & 63) == 0) wsum[tid >> 6] = ss;
        __syncthreads();
        float inv = 1.0f / fmaxf(sqrtf(wsum[0] + wsum[1]), EPS_);
        #pragma unroll
        for (int t = 0; t < 3; ++t) {
            int idx = tid + t * 128;
            if (idx < PLUP_) out[idx] = (idx < PLU_) ? f2b(vals[t] * inv) : (ushort)0;
        }
        __syncthreads();
    }
}

// ---------------------------------------------------------------------------
__global__ __launch_bounds__(256) void embed_k(
    const int* __restrict__ ids, const float* __restrict__ tok,
    const float* __restrict__ pos, float* __restrict__ x)
{
    int idx4 = blockIdx.x * 256 + threadIdx.x;
    if (idx4 >= M_ * D_ / 4) return;
    int idx = idx4 * 4;
    int row = idx / D_;
    int d = idx - row * D_;
    int l = row & (L_ - 1);
    float4 t = *reinterpret_cast<const float4*>(tok + (size_t)ids[row] * D_ + d);
    float4 p = *reinterpret_cast<const float4*>(pos + (size_t)l * D_ + d);
    float4 o = make_float4(t.x + p.x, t.y + p.y, t.z + p.z, t.w + p.w);
    *reinterpret_cast<float4*>(x + idx) = o;
}

__global__ __launch_bounds__(256) void cvt_k(
    const float* __restrict__ src, ushort* __restrict__ dst, int n4)
{
    int idx4 = blockIdx.x * 256 + threadIdx.x;
    if (idx4 >= n4) return;
    float4 v = *reinterpret_cast<const float4*>(src + idx4 * 4);
    *reinterpret_cast<ushort4*>(dst + idx4 * 4) = f4b4(v);
}

// per-layer weight conversion (gp1 padded 276->288, gp2, gate, fc1, fc2)
#define WC_G1  73728
#define WC_G2  (WC_G1 + 163840)
#define WC_GT  (WC_G2 + 819200)
#define WC_F1  (WC_GT + 1638400)
#define WC_F2  (WC_F1 + 1638400)
__global__ __launch_bounds__(256) void wconv_all_k(
    const float* __restrict__ g1, const float* __restrict__ g2,
    const float* __restrict__ gt, const float* __restrict__ f1,
    const float* __restrict__ f2, ushort* __restrict__ wb_all)
{
    int l = blockIdx.y;
    int idx4 = blockIdx.x * 256 + threadIdx.x;
    int idx = idx4 * 4;
    if (idx >= WC_F2) return;
    ushort* wb = wb_all + (size_t)l * WC_F2;
    float4 v;
    if (idx < WC_G1) {
        const float* s = g1 + (size_t)l * DG_ * PLU_;
        int row = idx / PLUP_, c = idx - row * PLUP_;
        if (c < PLU_) v = *reinterpret_cast<const float4*>(s + (size_t)row * PLU_ + c);
        else          v = make_float4(0.f, 0.f, 0.f, 0.f);
    } else if (idx < WC_G2) {
        v = *reinterpret_cast<const float4*>(g2 + (size_t)l * D_ * DG_ + (idx - WC_G1));
    } else if (idx < WC_GT) {
        v = *reinterpret_cast<const float4*>(gt + (size_t)l * D_ * 2 * D_ + (idx - WC_G2));
    } else if (idx < WC_F1) {
        v = *reinterpret_cast<const float4*>(f1 + (size_t)l * DF_ * D_ + (idx - WC_GT));
    } else {
        v = *reinterpret_cast<const float4*>(f2 + (size_t)l * D_ * DF_ + (idx - WC_F1));
    }
    *reinterpret_cast<ushort4*>(wb + idx) = f4b4(v);
}

// ---------------------------------------------------------------------------
__global__ __launch_bounds__(128) void ln_k(
    const float* __restrict__ x, const float* __restrict__ w,
    const float* __restrict__ b, float* __restrict__ outf,
    ushort* __restrict__ outb, int bstride)
{
    int row = blockIdx.x;
    int tid = threadIdx.x;
    const float* xr = x + (size_t)row * D_;
    float v[5];
    float sum = 0.f, sumsq = 0.f;
    #pragma unroll
    for (int t = 0; t < 5; ++t) {
        v[t] = xr[tid + t * 128];
        sum += v[t]; sumsq += v[t] * v[t];
    }
    #pragma unroll
    for (int off = 32; off > 0; off >>= 1) {
        sum += __shfl_down(sum, off);
        sumsq += __shfl_down(sumsq, off);
    }
    __shared__ float s0[2], s1[2];
    if ((tid & 63) == 0) { s0[tid >> 6] = sum; s1[tid >> 6] = sumsq; }
    __syncthreads();
    float m = (s0[0] + s0[1]) * (1.0f / D_);
    float var = (s1[0] + s1[1]) * (1.0f / D_) - m * m;
    float inv = rsqrtf(var + LN_EPS_);
    #pragma unroll
    for (int t = 0; t < 5; ++t) {
        int d = tid + t * 128;
        float o = (v[t] - m) * inv * w[d] + b[d];
        if (outf) outf[(size_t)row * D_ + d] = o;
        if (outb) outb[(size_t)row * bstride + d] = f2b(o);
    }
}

// ---------------------------------------------------------------------------
static void mg64(int epi, const ushort* A, const ushort* W, const float* bias,
                 float* Cf, const ushort* hg, ushort* ub,
                 int M, int N, int K, hipStream_t s)
{
    dim3 grid(M / 64, N / 64), block(256);
    if (epi == 2)      mgemm64_k<2><<<grid, block, 0, s>>>(A, W, bias, Cf, hg, ub, M, N, K);
    else if (epi == 3) mgemm64_k<3><<<grid, block, 0, s>>>(A, W, bias, Cf, hg, ub, M, N, K);
    else               mgemm64_k<5><<<grid, block, 0, s>>>(A, W, bias, Cf, hg, ub, M, N, K);
}

extern "C" void kernel_launch(void* const* d_in, const int* in_sizes, int n_in,
                              void* d_out, int out_size, void* d_ws, size_t ws_size,
                              hipStream_t stream)
{
    const int*   ids   = (const int*)d_in[0];
    const float* tok   = (const float*)d_in[1];
    const float* pos   = (const float*)d_in[2];
    const float* ln1w  = (const float*)d_in[3];
    const float* ln1b  = (const float*)d_in[4];
    const float* redw  = (const float*)d_in[5];
    const float* redb  = (const float*)d_in[6];
    const float* gp1w  = (const float*)d_in[7];
    const float* gp1b  = (const float*)d_in[8];
    const float* gp2w  = (const float*)d_in[9];
    const float* gp2b  = (const float*)d_in[10];
    const float* gatew = (const float*)d_in[11];
    const float* gateb = (const float*)d_in[12];
    const float* ln2w  = (const float*)d_in[13];
    const float* ln2b  = (const float*)d_in[14];
    const float* fc1w  = (const float*)d_in[15];
    const float* fc1b  = (const float*)d_in[16];
    const float* fc2w  = (const float*)d_in[17];
    const float* fc2b  = (const float*)d_in[18];
    const float* fnw   = (const float*)d_in[19];
    const float* fnb   = (const float*)d_in[20];
    float* out = (float*)d_out;

    const size_t MD = (size_t)M_ * D_;
    float* ws = (float*)d_ws;
    float* x = ws;                       // MD f32
    float* z = x + MD;                   // M_*R_ f32
    ushort* pb    = (ushort*)(z + (size_t)M_ * R_);       // 7*M_*288
    ushort* c1b   = pb + (size_t)7 * M_ * PLUP_;          // 7*M_*256
    ushort* crb   = c1b + (size_t)7 * M_ * DG_;           // M_*256
    ushort* hgb   = crb + (size_t)M_ * DG_;               // M_*1280
    ushort* h2b   = hgb + (size_t)M_ * 2 * D_;            // M_*640
    ushort* ffb   = h2b + MD;                             // M_*2560
    ushort* xnb   = ffb + (size_t)M_ * DF_;               // M_*640
    ushort* tokb  = xnb + MD;                             // V_*640
    ushort* wb    = tokb + (size_t)V_ * D_;               // WC_F2 (or x16)

    const size_t base_bytes = (size_t)((char*)wb - (char*)d_ws);
    const bool all_w = ws_size >= base_bytes + (size_t)NL_ * WC_F2 * 2;

    const int WC_GRID4 = (WC_F2 / 4 + 255) / 256;

    embed_k<<<(M_ * D_ / 4 + 255) / 256, 256, 0, stream>>>(ids, tok, pos, x);
    cvt_k<<<(V_ * D_ / 4 + 255) / 256, 256, 0, stream>>>(tok, tokb, V_ * D_ / 4);
    if (all_w)
        wconv_all_k<<<dim3(WC_GRID4, NL_), 256, 0, stream>>>(gp1w, gp2w, gatew, fc1w, fc2w, wb);

    for (int l = 0; l < NL_; ++l) {
        const ushort* wbl = all_w ? wb + (size_t)l * WC_F2 : wb;
        if (!all_w)
            wconv_all_k<<<dim3(WC_GRID4, 1), 256, 0, stream>>>(
                gp1w + (size_t)l * DG_ * PLU_, gp2w + (size_t)l * D_ * DG_,
                gatew + (size_t)l * D_ * 2 * D_, fc1w + (size_t)l * DF_ * D_,
                fc2w + (size_t)l * D_ * DF_, wb);
        lnred_k<<<M_, 128, 0, stream>>>(x, ln1w + (size_t)l * D_, ln1b + (size_t)l * D_,
                                        redw + (size_t)l * R_ * D_, redb + (size_t)l * R_,
                                        hgb, z);
        plucker_all_k<<<M_, 128, 0, stream>>>(z, pb);
        // gp1: 128x64 tile (896 blocks)
        {
            dim3 grid(7 * M_ / 128, DG_ / 64), block(256);
            mgemm12864_k<<<grid, block, 0, stream>>>(pb, wbl, gp1b + (size_t)l * DG_,
                                                     c1b, 7 * M_, DG_, PLUP_);
        }
        credsum_k<<<(M_ * DG_ / 4 + 255) / 256, 256, 0, stream>>>(c1b, crb);
        // gp2 on M rows (linearity fusion): g -> bf16 into hgb[.,D..2D); 640 blocks
        mg64(5, crb, wbl + WC_G1, gp2b + (size_t)l * D_, nullptr, hgb, hgb,
             M_, D_, DG_, stream);
        // gate fused with x-update; h,g read from bf16 hgb; 640 blocks
        mg64(2, hgb, wbl + WC_G2, gateb + (size_t)l * D_, x, hgb, nullptr,
             M_, D_, 2 * D_, stream);
        ln_k<<<M_, 128, 0, stream>>>(x, ln2w + (size_t)l * D_, ln2b + (size_t)l * D_,
                                     nullptr, h2b, D_);
        // fc1: 128x64 tile (1280 blocks)
        {
            dim3 grid(M_ / 128, DF_ / 64), block(256);
            mgemm12864_k<<<grid, block, 0, stream>>>(h2b, wbl + WC_GT,
                                                     fc1b + (size_t)l * DF_,
                                                     ffb, M_, DF_, D_);
        }
        // fc2 accumulate into x; 640 blocks
        mg64(3, ffb, wbl + WC_F1, fc2b + (size_t)l * D_, x, nullptr, nullptr,
             M_, D_, DF_, stream);
    }
    ln_k<<<M_, 128, 0, stream>>>(x, fnw, fnb, nullptr, xnb, D_);
    {   // lm_head: 256x128 tile + 2-phase + nontemporal stores
        dim3 grid(M_ / 256, (V_ + 127) / 128), block(512);
        mgemm256nt_k<<<grid, block, 0, stream>>>(xnb, tokb, out, M_, V_, D_);
    }
}